// Round 14
// baseline (302.338 us; speedup 1.0000x reference)
//
#include <hip/hip_runtime.h>
#include <hip/hip_bf16.h>

// ---------------------------------------------------------------------------
// EnhancedTernaryLinear: out = (x @ W^T) * scale + bias
// M=8192, N=4096, K=4096. Fused x->bf16 / W->bf16 conversion, then MFMA GEMM.
// R14: TWO-BLOCKS-PER-CU structure. 128x256 block tile, 8 waves (2x4) of
// 64x64 (acc = 64 AGPR), BK=32, 48 KiB LDS double-buffer -> 2 independent
// barrier groups per CU so one block's LDS/stage phase overlaps the other's
// MFMA phase. __launch_bounds__(512,4) pins the 128-reg/wave budget.
// ---------------------------------------------------------------------------

#define M_DIM 8192
#define N_DIM 4096
#define K_DIM 4096
#define BK 32
#define NTT (K_DIM / BK)   // 128 K-tiles

typedef __attribute__((ext_vector_type(8))) short bf16x8;
typedef __attribute__((ext_vector_type(4))) float f32x4;

__device__ __forceinline__ unsigned short f2bf(float f) {
  unsigned int u = __float_as_uint(f);
  unsigned int r = (u + 0x7FFFu + ((u >> 16) & 1u)) >> 16;
  return (unsigned short)r;
}

__device__ __forceinline__ unsigned short i2bf(int v) {
  return v == 0 ? (unsigned short)0
                : (v > 0 ? (unsigned short)0x3F80 : (unsigned short)0xBF80);
}

__device__ __forceinline__ void async16(const void* g, void* l) {
  __builtin_amdgcn_global_load_lds(
      (const __attribute__((address_space(1))) void*)g,
      (__attribute__((address_space(3))) void*)l, 16, 0, 0);
}

// ---------------- fused conversion kernel (one launch) ----------------

__global__ void cvt_fused_kernel(const float* __restrict__ x,
                                 const int* __restrict__ w,
                                 unsigned short* __restrict__ xb,
                                 unsigned short* __restrict__ wb,
                                 long nx, long nw) {
  long i0 = ((long)blockIdx.x * blockDim.x + threadIdx.x) * 8;
  long stride = (long)gridDim.x * blockDim.x * 8;
  for (long i = i0; i < nx; i += stride) {
    float4 v0 = *(const float4*)(x + i);
    float4 v1 = *(const float4*)(x + i + 4);
    bf16x8 o;
    o[0] = (short)f2bf(v0.x); o[1] = (short)f2bf(v0.y);
    o[2] = (short)f2bf(v0.z); o[3] = (short)f2bf(v0.w);
    o[4] = (short)f2bf(v1.x); o[5] = (short)f2bf(v1.y);
    o[6] = (short)f2bf(v1.z); o[7] = (short)f2bf(v1.w);
    *(bf16x8*)(xb + i) = o;
  }
  for (long i = i0; i < nw; i += stride) {
    int4 a = *(const int4*)(w + i);
    int4 b = *(const int4*)(w + i + 4);
    bf16x8 o;
    o[0] = (short)i2bf(a.x); o[1] = (short)i2bf(a.y);
    o[2] = (short)i2bf(a.z); o[3] = (short)i2bf(a.w);
    o[4] = (short)i2bf(b.x); o[5] = (short)i2bf(b.y);
    o[6] = (short)i2bf(b.z); o[7] = (short)i2bf(b.w);
    *(bf16x8*)(wb + i) = o;
  }
}

// ---------------- 128x256 GEMM block, 2 blocks/CU ----------------
// 512 threads = 8 waves (2 wr x 4 wc), wave tile 64x64 = 4x4 frags 16x16x32,
// acc = 16 x f32x4 = 64 AGPR.
// LDS 48 KiB (ushort lds[24576]): buf b at byte b*24576:
//   A: 128 rows x 64 B at +0;  B: 256 rows x 64 B at +8192.
// Swizzle (64-B rows, R6-verified): stored byte col = logical ^
//   (((row>>1)&3)<<4). Staged via inverse-swizzled GLOBAL source + linear
//   LDS dest (rule 21); read with swizzled per-lane col (fq*16 ^ sl).
// Per tile T (buf CB, other NB):
//   - stage A(T+1), B(T+1) -> NB (3 async16/thread)
//   - issue 8 ds_read_b128: bF0,bF1, aF0..3, bF2,bF3  (from CB)
//   - LGKM(2) -> MFMA ni=0,1 (8);  LGKM(0) -> MFMA ni=2,3 (8)
//   - VMW(0) (stages landed; ~2 MFMA clusters of cover + cross-block TLP)
//   - barrier  (one per tile)
// WAR safe: stages touch NB only; reads of CB drained at LGKM(0) pre-barrier.

#define DSR(dst, base, OFF)                                     \
  asm volatile("ds_read_b128 %0, %1 offset:" OFF                \
               : "=v"(dst) : "v"(base))
#define LGKM(N)                                                  \
  asm volatile("s_waitcnt lgkmcnt(" #N ")" ::: "memory");        \
  __builtin_amdgcn_sched_barrier(0)
#define VMW(N) asm volatile("s_waitcnt vmcnt(" #N ")" ::: "memory")

#define MFMA_NI2(NI0, NI1)                                                     \
  do {                                                                         \
    __builtin_amdgcn_s_setprio(1);                                             \
    _Pragma("unroll") for (int mi = 0; mi < 4; ++mi)                           \
      acc[mi][NI0] = __builtin_amdgcn_mfma_f32_16x16x32_bf16(                  \
          aF[mi], bF[NI0], acc[mi][NI0], 0, 0, 0);                             \
    _Pragma("unroll") for (int mi = 0; mi < 4; ++mi)                           \
      acc[mi][NI1] = __builtin_amdgcn_mfma_f32_16x16x32_bf16(                  \
          aF[mi], bF[NI1], acc[mi][NI1], 0, 0, 0);                             \
    __builtin_amdgcn_s_setprio(0);                                             \
    __builtin_amdgcn_sched_barrier(0);                                         \
  } while (0)

// CBB/NBB: current/next buf BYTE offsets (0 / 24576)
#define TILE(TT, CBB, NBB)                                                     \
  do {                                                                         \
    const int T_ = (TT);                                                       \
    if (T_ + 1 < NTT) {                                                        \
      const unsigned short* Ag = Ablk + ((T_ + 1) << 5);                       \
      const unsigned short* Bg = Bblk + ((T_ + 1) << 5);                       \
      async16(Ag + srcA, lds + (NBB) / 2 + t * 8);                             \
      async16(Bg + srcA, lds + (NBB) / 2 + 4096 + t * 8);                      \
      async16(Bg + srcB1, lds + (NBB) / 2 + 8192 + t * 8);                     \
    }                                                                          \
    DSR(bF[0], rB + (CBB), "0");    DSR(bF[1], rB + (CBB), "1024");            \
    DSR(aF[0], rA + (CBB), "0");    DSR(aF[1], rA + (CBB), "1024");            \
    DSR(aF[2], rA + (CBB), "2048"); DSR(aF[3], rA + (CBB), "3072");            \
    DSR(bF[2], rB + (CBB), "2048"); DSR(bF[3], rB + (CBB), "3072");            \
    LGKM(2);   /* bF01 + aF0..3 ready */                                       \
    MFMA_NI2(0, 1);                                                            \
    LGKM(0);   /* bF23 ready */                                                \
    MFMA_NI2(2, 3);                                                            \
    VMW(0);    /* T+1 stages landed */                                         \
    __builtin_amdgcn_s_barrier();                                              \
  } while (0)

__global__ void __launch_bounds__(512, 4)
gemm_bt_kernel(const unsigned short* __restrict__ A,  // bf16 [M][K]
               const unsigned short* __restrict__ B,  // bf16 [N][K]
               const float* __restrict__ scale, const float* __restrict__ bias,
               float* __restrict__ C) {
  __shared__ unsigned short lds[24576];  // 48 KiB

  const int t = threadIdx.x;
  const int bid = blockIdx.x;
  const int swz = (bid & 7) * 128 + (bid >> 3);  // 1024 wgs, 128/XCD bijective
  const int bm = swz >> 4;  // 64 M-tiles (128 rows)
  const int bn = swz & 15;  // 16 N-tiles (256 cols)
  const int brow = bm * 128, bcol = bn * 256;

  const int wid = t >> 6, lane = t & 63;
  const int wr = wid >> 2, wc = wid & 3;
  const int fr = lane & 15, fq = lane >> 4;

  // staging source offsets (elements); rows 0..127 domain, swizzle slot
  // ((row>>1)&3)<<4 — identical for row and row+128 (128%4==0)
  const int colb = (t & 3) * 16;           // logical byte col in 64-B row
  const int sa = t >> 2;                   // 0..127
  const int ssw = ((sa >> 1) & 3) << 4;
  const unsigned srcA = (unsigned)(sa * K_DIM + ((colb ^ ssw) >> 1));
  const unsigned srcB1 = srcA + 128u * K_DIM;

  const unsigned short* Ablk = A + (size_t)brow * K_DIM;
  const unsigned short* Bblk = B + (size_t)bcol * K_DIM;

  // ds_read bases (byte addrs), swizzle folded per-lane
  const unsigned ldsb = (unsigned)(unsigned long long)&lds[0];
  const unsigned sl = (unsigned)(((fr >> 1) & 3) << 4);
  const unsigned cc = ((unsigned)(fq * 16)) ^ sl;
  const unsigned rA = ldsb + (unsigned)((wr * 64 + fr) * 64) + cc;
  const unsigned rB = ldsb + 8192u + (unsigned)((wc * 64 + fr) * 64) + cc;

  f32x4 acc[4][4] = {};
  bf16x8 aF[4], bF[4];

  // ---- prologue: stage tile0 -> buf0 ----
  async16(Ablk + srcA, lds + t * 8);
  async16(Bblk + srcA, lds + 4096 + t * 8);
  async16(Bblk + srcB1, lds + 8192 + t * 8);
  VMW(0);
  __builtin_amdgcn_s_barrier();

  for (int T = 0; T < NTT; T += 2) {
    TILE(T, 0, 24576);
    TILE(T + 1, 24576, 0);
  }

  // ---- epilogue: scale/bias, C/D layout col=lane&15, row=(lane>>4)*4+j ----
#pragma unroll
  for (int ni = 0; ni < 4; ++ni) {
    const int gc = bcol + wc * 64 + ni * 16 + fr;
    const float s = scale[gc];
    const float bo = bias[gc];
#pragma unroll
    for (int mi = 0; mi < 4; ++mi) {
      const int gr = brow + wr * 64 + mi * 16 + fq * 4;
#pragma unroll
      for (int j = 0; j < 4; ++j)
        C[(size_t)(gr + j) * N_DIM + gc] = acc[mi][ni][j] * s + bo;
    }
  }
}

// ---------------- naive fallback (only if ws too small) ----------------

__global__ void naive_kernel(const float* __restrict__ x, const int* __restrict__ w,
                             const float* __restrict__ sc, const float* __restrict__ bi,
                             float* __restrict__ out) {
  size_t idx = (size_t)blockIdx.x * blockDim.x + threadIdx.x;
  int m = (int)(idx >> 12);
  int n = (int)(idx & 4095);
  const float* xr = x + (size_t)m * K_DIM;
  const int* wr = w + (size_t)n * K_DIM;
  float acc = 0.f;
  for (int k = 0; k < K_DIM; ++k) acc = fmaf(xr[k], (float)wr[k], acc);
  out[idx] = acc * sc[n] + bi[n];
}

extern "C" void kernel_launch(void* const* d_in, const int* in_sizes, int n_in,
                              void* d_out, int out_size, void* d_ws, size_t ws_size,
                              hipStream_t stream) {
  const float* x = (const float*)d_in[0];
  const int* w = (const int*)d_in[1];
  const float* scale = (const float*)d_in[2];
  const float* bias = (const float*)d_in[3];
  float* out = (float*)d_out;

  const long nx = (long)M_DIM * K_DIM;
  const long nw = (long)N_DIM * K_DIM;
  const size_t need = (size_t)nx * 2 + (size_t)nw * 2;  // 96 MiB

  if (ws_size >= need) {
    unsigned short* xb = (unsigned short*)d_ws;
    unsigned short* wb = xb + nx;
    cvt_fused_kernel<<<2048, 256, 0, stream>>>(x, w, xb, wb, nx, nw);
    gemm_bt_kernel<<<1024, 512, 0, stream>>>(xb, wb, scale, bias, out);
  } else {
    naive_kernel<<<((long)M_DIM * N_DIM) / 256, 256, 0, stream>>>(x, w, scale, bias, out);
  }
}

// Round 15
// 259.496 us; speedup vs baseline: 1.1651x; 1.1651x over previous
//
#include <hip/hip_runtime.h>
#include <hip/hip_bf16.h>

// ---------------------------------------------------------------------------
// EnhancedTernaryLinear: out = (x @ W^T) * scale + bias
// M=8192, N=4096, K=4096. Fused x->bf16 / W->bf16 conversion (one launch),
// then the R5 champion 256x256 MFMA GEMM: 4-phase read-ahead pipeline,
// counted lgkmcnt + sched_barrier, one barrier per phase, XOR-swizzled LDS
// (0 conflicts), XCD-swizzled grid. Final configuration (R13 restored).
// ---------------------------------------------------------------------------

#define M_DIM 8192
#define N_DIM 4096
#define K_DIM 4096
#define BK 64
#define NT (K_DIM / BK)   // 64 K-tiles

typedef __attribute__((ext_vector_type(8))) short bf16x8;
typedef __attribute__((ext_vector_type(4))) float f32x4;

__device__ __forceinline__ unsigned short f2bf(float f) {
  unsigned int u = __float_as_uint(f);
  unsigned int r = (u + 0x7FFFu + ((u >> 16) & 1u)) >> 16;
  return (unsigned short)r;
}

__device__ __forceinline__ unsigned short i2bf(int v) {
  return v == 0 ? (unsigned short)0
                : (v > 0 ? (unsigned short)0x3F80 : (unsigned short)0xBF80);
}

__device__ __forceinline__ void async16(const void* g, void* l) {
  __builtin_amdgcn_global_load_lds(
      (const __attribute__((address_space(1))) void*)g,
      (__attribute__((address_space(3))) void*)l, 16, 0, 0);
}

// ---------------- fused conversion kernel (one launch) ----------------

__global__ void cvt_fused_kernel(const float* __restrict__ x,
                                 const int* __restrict__ w,
                                 unsigned short* __restrict__ xb,
                                 unsigned short* __restrict__ wb,
                                 long nx, long nw) {
  long i0 = ((long)blockIdx.x * blockDim.x + threadIdx.x) * 8;
  long stride = (long)gridDim.x * blockDim.x * 8;
  for (long i = i0; i < nx; i += stride) {
    float4 v0 = *(const float4*)(x + i);
    float4 v1 = *(const float4*)(x + i + 4);
    bf16x8 o;
    o[0] = (short)f2bf(v0.x); o[1] = (short)f2bf(v0.y);
    o[2] = (short)f2bf(v0.z); o[3] = (short)f2bf(v0.w);
    o[4] = (short)f2bf(v1.x); o[5] = (short)f2bf(v1.y);
    o[6] = (short)f2bf(v1.z); o[7] = (short)f2bf(v1.w);
    *(bf16x8*)(xb + i) = o;
  }
  for (long i = i0; i < nw; i += stride) {
    int4 a = *(const int4*)(w + i);
    int4 b = *(const int4*)(w + i + 4);
    bf16x8 o;
    o[0] = (short)i2bf(a.x); o[1] = (short)i2bf(a.y);
    o[2] = (short)i2bf(a.z); o[3] = (short)i2bf(a.w);
    o[4] = (short)i2bf(b.x); o[5] = (short)i2bf(b.y);
    o[6] = (short)i2bf(b.z); o[7] = (short)i2bf(b.w);
    *(bf16x8*)(wb + i) = o;
  }
}

// ---------------- 256x256 GEMM, 4 phases/K-tile, read-ahead 1 phase -------
// 512 threads = 8 waves (2 wr x 4 wc). Per-wave output 128x64 = 8x4 frags.
// LDS regions (ushort offsets), 128 KiB:
//   A (buf,mh): buf*32768 + mh*8192        (128 rows x 64 cols bf16)
//   B (buf,nh): buf*32768 + 16384 + nh*8192
// Swizzle: LDS[rho][bytecol ^ ((rho&7)<<4)]; staged via inverse-swizzled
// GLOBAL source + linear LDS dest, read with swizzled offset. 0 conflicts.
//
// MFMA usage: q0:(aFx,bF0) q1:(aFx,bF1) q2:(aFy,bF1) q3:(aFy,bF0).
// Reads issued (consumed NEXT phase):  q0: bF1(T) [4]; q1: aFy(T) [8];
//   q2: none; q3: aFx(T+1)+bF0n(T+1) [12].
// Waits before MFMA: q0 lgkm(4), q1 lgkm(8), q2 lgkm(0), q3 lgkm(12).
// Stages (global_load_lds): q0 -> B-nh0(T+1); q1 -> A-mh0(T+2);
//   q2 -> B-nh1(T+2); q3 -> A-mh1(T+2). vmcnt(4) at q2-end retires all of
//   tile T+1's staging (incl. q0(T)'s B-nh0) before q3's reads of it.
// One s_barrier per phase (end). Every stage targets a region whose last
// reads drained at the preceding phase's counted lgkm wait -> WAR safe.

#define AOFF(b, mh) ((b)*32768 + (mh)*8192)
#define BOFF(b, nh) ((b)*32768 + 16384 + (nh)*8192)

__device__ __forceinline__ void stage_A_half(const unsigned short* __restrict__ A,
                                             int grow0, int ktE, int mh,
                                             unsigned short* lds_region, int t) {
  const int colb = (t & 7) * 16;
  const int swz = ((t >> 3) & 7) << 4;
  const int scol = (colb ^ swz) >> 1;  // element offset in row
#pragma unroll
  for (int rr = 0; rr < 2; ++rr) {
    int rho = rr * 64 + (t >> 3);
    int r = ((rho >> 6) << 7) + mh * 64 + (rho & 63);
    async16(A + (size_t)(grow0 + r) * K_DIM + ktE + scol,
            lds_region + rr * 4096 + t * 8);
  }
}

__device__ __forceinline__ void stage_B_half(const unsigned short* __restrict__ B,
                                             int gcol0, int ktE, int nh,
                                             unsigned short* lds_region, int t) {
  const int colb = (t & 7) * 16;
  const int swz = ((t >> 3) & 7) << 4;
  const int scol = (colb ^ swz) >> 1;
#pragma unroll
  for (int rr = 0; rr < 2; ++rr) {
    int rho = rr * 64 + (t >> 3);
    int c = ((rho >> 5) << 6) + nh * 32 + (rho & 31);
    async16(B + (size_t)(gcol0 + c) * K_DIM + ktE + scol,
            lds_region + rr * 4096 + t * 8);
  }
}

// Inline-asm ds_read_b128: guaranteed width (lgkm counts depend on it).
#define DSR(dst, base, OFF)                                     \
  asm volatile("ds_read_b128 %0, %1 offset:" OFF                \
               : "=v"(dst) : "v"(base))

__device__ __forceinline__ void rd_a(unsigned b0, bf16x8 aF[4][2]) {
  unsigned b1 = b0 ^ 64;  // kk=1 (byte col ^64, swizzle-compatible)
  DSR(aF[0][0], b0, "0");    DSR(aF[0][1], b1, "0");
  DSR(aF[1][0], b0, "2048"); DSR(aF[1][1], b1, "2048");
  DSR(aF[2][0], b0, "4096"); DSR(aF[2][1], b1, "4096");
  DSR(aF[3][0], b0, "6144"); DSR(aF[3][1], b1, "6144");
}
__device__ __forceinline__ void rd_b(unsigned b0, bf16x8 bF[2][2]) {
  unsigned b1 = b0 ^ 64;
  DSR(bF[0][0], b0, "0");    DSR(bF[0][1], b1, "0");
  DSR(bF[1][0], b0, "2048"); DSR(bF[1][1], b1, "2048");
}

#define LGKM(N)                                                  \
  asm volatile("s_waitcnt lgkmcnt(" #N ")" ::: "memory");        \
  __builtin_amdgcn_sched_barrier(0)
#define VMW(N) asm volatile("s_waitcnt vmcnt(" #N ")" ::: "memory")

#define MFMA16(AF, BF, MH, NH)                                                 \
  do {                                                                         \
    __builtin_amdgcn_s_setprio(1);                                             \
    _Pragma("unroll") for (int kk = 0; kk < 2; ++kk)                           \
    _Pragma("unroll") for (int mi = 0; mi < 4; ++mi)                           \
    _Pragma("unroll") for (int ni = 0; ni < 2; ++ni)                           \
      acc[(MH)*4 + mi][(NH)*2 + ni] = __builtin_amdgcn_mfma_f32_16x16x32_bf16( \
          AF[mi][kk], BF[ni][kk], acc[(MH)*4 + mi][(NH)*2 + ni], 0, 0, 0);     \
    __builtin_amdgcn_s_setprio(0);                                             \
    __builtin_amdgcn_sched_barrier(0);                                         \
  } while (0)

__global__ void __launch_bounds__(512, 2)
gemm_bt_kernel(const unsigned short* __restrict__ A,  // bf16 [M][K]
               const unsigned short* __restrict__ B,  // bf16 [N][K]
               const float* __restrict__ scale, const float* __restrict__ bias,
               float* __restrict__ C) {
  __shared__ unsigned short lds[65536];  // 128 KiB

  const int t = threadIdx.x;
  const int bid = blockIdx.x;
  const int swz = (bid & 7) * 64 + (bid >> 3);  // 512 wgs, 64/XCD (bijective)
  const int bm = swz >> 4;  // 32 M-tiles
  const int bn = swz & 15;  // 16 N-tiles
  const int brow = bm * 256, bcol = bn * 256;

  const int wid = t >> 6, lane = t & 63;
  const int wr = wid >> 2, wc = wid & 3;
  const int fr = lane & 15, fq = lane >> 4;

  // ds_read base addresses (LDS byte offsets; low 32 bits of generic ptr)
  const unsigned ldsb = (unsigned)(unsigned long long)&lds[0];
  const unsigned swzcol = ((unsigned)(fq * 16)) ^ ((unsigned)((fr & 7) << 4));
  const unsigned rcA = ldsb + (unsigned)((wr * 64 + fr) * 128) + swzcol;
  const unsigned rcB = ldsb + (unsigned)((wc * 32 + fr) * 128) + swzcol;

  f32x4 acc[8][4] = {};
  bf16x8 aFx[4][2], aFy[4][2], bF0[2][2], bF1[2][2], bF0n[2][2];

  // ---- prologue: tile0 (4 halves) + tile1 {A-mh0, B-nh1, A-mh1} ----
  stage_A_half(A, brow, 0, 0, lds + AOFF(0, 0), t);
  stage_B_half(B, bcol, 0, 1, lds + BOFF(0, 1), t);
  stage_A_half(A, brow, 0, 1, lds + AOFF(0, 1), t);
  stage_B_half(B, bcol, 0, 0, lds + BOFF(0, 0), t);
  stage_A_half(A, brow, BK, 0, lds + AOFF(1, 0), t);
  stage_B_half(B, bcol, BK, 1, lds + BOFF(1, 1), t);
  stage_A_half(A, brow, BK, 1, lds + AOFF(1, 1), t);
  VMW(6);  // tile0's 8 stage-loads landed
  __builtin_amdgcn_s_barrier();
  // q3(-1) role: read tile0's aFx + bF0 (12 outstanding entering the loop)
  rd_a(rcA + ((unsigned)AOFF(0, 0) << 1), aFx);
  rd_b(rcB + ((unsigned)BOFF(0, 0) << 1), bF0);

  for (int T = 0; T < NT; ++T) {
    const int b = T & 1;

    // -- q0: MFMA(mh0,nh0); issue bF1(T) reads; stage B-nh0(T+1)
    rd_b(rcB + ((unsigned)BOFF(b, 1) << 1), bF1);
    if (T + 1 < NT) stage_B_half(B, bcol, (T + 1) * BK, 0, lds + BOFF(b ^ 1, 0), t);
    LGKM(4);  // aFx + bF0 (issued last phase) drained; own 4 may pend
    MFMA16(aFx, bF0, 0, 0);
    __builtin_amdgcn_s_barrier();

    // -- q1: MFMA(mh0,nh1); issue aFy(T) reads; stage A-mh0(T+2)
    rd_a(rcA + ((unsigned)AOFF(b, 1) << 1), aFy);
    if (T + 2 < NT) stage_A_half(A, brow, (T + 2) * BK, 0, lds + AOFF(b, 0), t);
    LGKM(8);  // bF1 drained; own 8 may pend
    MFMA16(aFx, bF1, 0, 1);
    __builtin_amdgcn_s_barrier();

    // -- q2: MFMA(mh1,nh1); no reads; stage B-nh1(T+2); vmcnt once/tile
    if (T + 2 < NT) stage_B_half(B, bcol, (T + 2) * BK, 1, lds + BOFF(b, 1), t);
    LGKM(0);  // aFy drained (issued a full phase ago -> ~free)
    MFMA16(aFy, bF1, 1, 1);
    if (T < NT - 2)
      VMW(4);  // retires all tile-T+1 staging (outstanding = q1,q2 stages)
    else if (T == NT - 2)
      VMW(0);  // final drain
    __builtin_amdgcn_s_barrier();

    // -- q3: MFMA(mh1,nh0); issue aFx'+bF0n(T+1) reads; stage A-mh1(T+2)
    if (T + 1 < NT) {
      rd_a(rcA + ((unsigned)AOFF(b ^ 1, 0) << 1), aFx);
      rd_b(rcB + ((unsigned)BOFF(b ^ 1, 0) << 1), bF0n);
      if (T + 2 < NT) stage_A_half(A, brow, (T + 2) * BK, 1, lds + AOFF(b, 1), t);
      LGKM(12);  // nothing older outstanding; own 12 may pend
      MFMA16(aFy, bF0, 1, 0);  // uses OLD bF0 (pre-reload SSA values)
#pragma unroll
      for (int ni = 0; ni < 2; ++ni)
#pragma unroll
        for (int kk = 0; kk < 2; ++kk) bF0[ni][kk] = bF0n[ni][kk];
    } else {
      LGKM(0);
      MFMA16(aFy, bF0, 1, 0);
    }
    __builtin_amdgcn_s_barrier();
  }

  // ---- epilogue: scale/bias, C/D layout col=lane&15, row=(lane>>4)*4+j ----
#pragma unroll
  for (int n = 0; n < 4; ++n) {
    const int gc = bcol + wc * 64 + n * 16 + fr;
    const float s = scale[gc];
    const float bo = bias[gc];
#pragma unroll
    for (int m = 0; m < 8; ++m) {
      const int gr = brow + wr * 128 + m * 16 + fq * 4;
#pragma unroll
      for (int j = 0; j < 4; ++j)
        C[(size_t)(gr + j) * N_DIM + gc] = acc[m][n][j] * s + bo;
    }
  }
}

// ---------------- naive fallback (only if ws too small) ----------------

__global__ void naive_kernel(const float* __restrict__ x, const int* __restrict__ w,
                             const float* __restrict__ sc, const float* __restrict__ bi,
                             float* __restrict__ out) {
  size_t idx = (size_t)blockIdx.x * blockDim.x + threadIdx.x;
  int m = (int)(idx >> 12);
  int n = (int)(idx & 4095);
  const float* xr = x + (size_t)m * K_DIM;
  const int* wr = w + (size_t)n * K_DIM;
  float acc = 0.f;
  for (int k = 0; k < K_DIM; ++k) acc = fmaf(xr[k], (float)wr[k], acc);
  out[idx] = acc * sc[n] + bi[n];
}

extern "C" void kernel_launch(void* const* d_in, const int* in_sizes, int n_in,
                              void* d_out, int out_size, void* d_ws, size_t ws_size,
                              hipStream_t stream) {
  const float* x = (const float*)d_in[0];
  const int* w = (const int*)d_in[1];
  const float* scale = (const float*)d_in[2];
  const float* bias = (const float*)d_in[3];
  float* out = (float*)d_out;

  const long nx = (long)M_DIM * K_DIM;
  const long nw = (long)N_DIM * K_DIM;
  const size_t need = (size_t)nx * 2 + (size_t)nw * 2;  // 96 MiB

  if (ws_size >= need) {
    unsigned short* xb = (unsigned short*)d_ws;
    unsigned short* wb = xb + nx;
    cvt_fused_kernel<<<2048, 256, 0, stream>>>(x, w, xb, wb, nx, nw);
    gemm_bt_kernel<<<512, 512, 0, stream>>>(xb, wb, scale, bias, out);
  } else {
    naive_kernel<<<((long)M_DIM * N_DIM) / 256, 256, 0, stream>>>(x, w, scale, bias, out);
  }
}

// Round 16
// 251.515 us; speedup vs baseline: 1.2021x; 1.0317x over previous
//
#include <hip/hip_runtime.h>
#include <hip/hip_bf16.h>

// ---------------------------------------------------------------------------
// EnhancedTernaryLinear: out = (x @ W^T) * scale + bias
// M=8192, N=4096, K=4096. Fused x->bf16 / W->bf16 conversion (one launch),
// then the R5 champion 256x256 MFMA GEMM (4-phase read-ahead pipeline,
// counted lgkmcnt + sched_barrier, one barrier per phase, XOR-swizzled LDS,
// XCD-swizzled grid). R16 = champion + LDS-transposed VECTORIZED epilogue
// (dwordx4 stores, 256B-per-lane-group contiguity; loop untouched).
// ---------------------------------------------------------------------------

#define M_DIM 8192
#define N_DIM 4096
#define K_DIM 4096
#define BK 64
#define NT (K_DIM / BK)   // 64 K-tiles

typedef __attribute__((ext_vector_type(8))) short bf16x8;
typedef __attribute__((ext_vector_type(4))) float f32x4;

__device__ __forceinline__ unsigned short f2bf(float f) {
  unsigned int u = __float_as_uint(f);
  unsigned int r = (u + 0x7FFFu + ((u >> 16) & 1u)) >> 16;
  return (unsigned short)r;
}

__device__ __forceinline__ unsigned short i2bf(int v) {
  return v == 0 ? (unsigned short)0
                : (v > 0 ? (unsigned short)0x3F80 : (unsigned short)0xBF80);
}

__device__ __forceinline__ void async16(const void* g, void* l) {
  __builtin_amdgcn_global_load_lds(
      (const __attribute__((address_space(1))) void*)g,
      (__attribute__((address_space(3))) void*)l, 16, 0, 0);
}

// ---------------- fused conversion kernel (one launch) ----------------

__global__ void cvt_fused_kernel(const float* __restrict__ x,
                                 const int* __restrict__ w,
                                 unsigned short* __restrict__ xb,
                                 unsigned short* __restrict__ wb,
                                 long nx, long nw) {
  long i0 = ((long)blockIdx.x * blockDim.x + threadIdx.x) * 8;
  long stride = (long)gridDim.x * blockDim.x * 8;
  for (long i = i0; i < nx; i += stride) {
    float4 v0 = *(const float4*)(x + i);
    float4 v1 = *(const float4*)(x + i + 4);
    bf16x8 o;
    o[0] = (short)f2bf(v0.x); o[1] = (short)f2bf(v0.y);
    o[2] = (short)f2bf(v0.z); o[3] = (short)f2bf(v0.w);
    o[4] = (short)f2bf(v1.x); o[5] = (short)f2bf(v1.y);
    o[6] = (short)f2bf(v1.z); o[7] = (short)f2bf(v1.w);
    *(bf16x8*)(xb + i) = o;
  }
  for (long i = i0; i < nw; i += stride) {
    int4 a = *(const int4*)(w + i);
    int4 b = *(const int4*)(w + i + 4);
    bf16x8 o;
    o[0] = (short)i2bf(a.x); o[1] = (short)i2bf(a.y);
    o[2] = (short)i2bf(a.z); o[3] = (short)i2bf(a.w);
    o[4] = (short)i2bf(b.x); o[5] = (short)i2bf(b.y);
    o[6] = (short)i2bf(b.z); o[7] = (short)i2bf(b.w);
    *(bf16x8*)(wb + i) = o;
  }
}

// ---------------- 256x256 GEMM, 4 phases/K-tile, read-ahead 1 phase -------
// (champion loop — unchanged from R5/R13; see prior round comments)

#define AOFF(b, mh) ((b)*32768 + (mh)*8192)
#define BOFF(b, nh) ((b)*32768 + 16384 + (nh)*8192)

__device__ __forceinline__ void stage_A_half(const unsigned short* __restrict__ A,
                                             int grow0, int ktE, int mh,
                                             unsigned short* lds_region, int t) {
  const int colb = (t & 7) * 16;
  const int swz = ((t >> 3) & 7) << 4;
  const int scol = (colb ^ swz) >> 1;  // element offset in row
#pragma unroll
  for (int rr = 0; rr < 2; ++rr) {
    int rho = rr * 64 + (t >> 3);
    int r = ((rho >> 6) << 7) + mh * 64 + (rho & 63);
    async16(A + (size_t)(grow0 + r) * K_DIM + ktE + scol,
            lds_region + rr * 4096 + t * 8);
  }
}

__device__ __forceinline__ void stage_B_half(const unsigned short* __restrict__ B,
                                             int gcol0, int ktE, int nh,
                                             unsigned short* lds_region, int t) {
  const int colb = (t & 7) * 16;
  const int swz = ((t >> 3) & 7) << 4;
  const int scol = (colb ^ swz) >> 1;
#pragma unroll
  for (int rr = 0; rr < 2; ++rr) {
    int rho = rr * 64 + (t >> 3);
    int c = ((rho >> 5) << 6) + nh * 32 + (rho & 31);
    async16(B + (size_t)(gcol0 + c) * K_DIM + ktE + scol,
            lds_region + rr * 4096 + t * 8);
  }
}

#define DSR(dst, base, OFF)                                     \
  asm volatile("ds_read_b128 %0, %1 offset:" OFF                \
               : "=v"(dst) : "v"(base))

__device__ __forceinline__ void rd_a(unsigned b0, bf16x8 aF[4][2]) {
  unsigned b1 = b0 ^ 64;  // kk=1 (byte col ^64, swizzle-compatible)
  DSR(aF[0][0], b0, "0");    DSR(aF[0][1], b1, "0");
  DSR(aF[1][0], b0, "2048"); DSR(aF[1][1], b1, "2048");
  DSR(aF[2][0], b0, "4096"); DSR(aF[2][1], b1, "4096");
  DSR(aF[3][0], b0, "6144"); DSR(aF[3][1], b1, "6144");
}
__device__ __forceinline__ void rd_b(unsigned b0, bf16x8 bF[2][2]) {
  unsigned b1 = b0 ^ 64;
  DSR(bF[0][0], b0, "0");    DSR(bF[0][1], b1, "0");
  DSR(bF[1][0], b0, "2048"); DSR(bF[1][1], b1, "2048");
}

#define LGKM(N)                                                  \
  asm volatile("s_waitcnt lgkmcnt(" #N ")" ::: "memory");        \
  __builtin_amdgcn_sched_barrier(0)
#define VMW(N) asm volatile("s_waitcnt vmcnt(" #N ")" ::: "memory")

#define MFMA16(AF, BF, MH, NH)                                                 \
  do {                                                                         \
    __builtin_amdgcn_s_setprio(1);                                             \
    _Pragma("unroll") for (int kk = 0; kk < 2; ++kk)                           \
    _Pragma("unroll") for (int mi = 0; mi < 4; ++mi)                           \
    _Pragma("unroll") for (int ni = 0; ni < 2; ++ni)                           \
      acc[(MH)*4 + mi][(NH)*2 + ni] = __builtin_amdgcn_mfma_f32_16x16x32_bf16( \
          AF[mi][kk], BF[ni][kk], acc[(MH)*4 + mi][(NH)*2 + ni], 0, 0, 0);     \
    __builtin_amdgcn_s_setprio(0);                                             \
    __builtin_amdgcn_sched_barrier(0);                                         \
  } while (0)

__global__ void __launch_bounds__(512, 2)
gemm_bt_kernel(const unsigned short* __restrict__ A,  // bf16 [M][K]
               const unsigned short* __restrict__ B,  // bf16 [N][K]
               const float* __restrict__ scale, const float* __restrict__ bias,
               float* __restrict__ C) {
  __shared__ unsigned short lds[65536];  // 128 KiB

  const int t = threadIdx.x;
  const int bid = blockIdx.x;
  const int swz = (bid & 7) * 64 + (bid >> 3);  // 512 wgs, 64/XCD (bijective)
  const int bm = swz >> 4;  // 32 M-tiles
  const int bn = swz & 15;  // 16 N-tiles
  const int brow = bm * 256, bcol = bn * 256;

  const int wid = t >> 6, lane = t & 63;
  const int wr = wid >> 2, wc = wid & 3;
  const int fr = lane & 15, fq = lane >> 4;

  // ds_read base addresses (LDS byte offsets; low 32 bits of generic ptr)
  const unsigned ldsb = (unsigned)(unsigned long long)&lds[0];
  const unsigned swzcol = ((unsigned)(fq * 16)) ^ ((unsigned)((fr & 7) << 4));
  const unsigned rcA = ldsb + (unsigned)((wr * 64 + fr) * 128) + swzcol;
  const unsigned rcB = ldsb + (unsigned)((wc * 32 + fr) * 128) + swzcol;

  f32x4 acc[8][4] = {};
  bf16x8 aFx[4][2], aFy[4][2], bF0[2][2], bF1[2][2], bF0n[2][2];

  // ---- prologue: tile0 (4 halves) + tile1 {A-mh0, B-nh1, A-mh1} ----
  stage_A_half(A, brow, 0, 0, lds + AOFF(0, 0), t);
  stage_B_half(B, bcol, 0, 1, lds + BOFF(0, 1), t);
  stage_A_half(A, brow, 0, 1, lds + AOFF(0, 1), t);
  stage_B_half(B, bcol, 0, 0, lds + BOFF(0, 0), t);
  stage_A_half(A, brow, BK, 0, lds + AOFF(1, 0), t);
  stage_B_half(B, bcol, BK, 1, lds + BOFF(1, 1), t);
  stage_A_half(A, brow, BK, 1, lds + AOFF(1, 1), t);
  VMW(6);  // tile0's 8 stage-loads landed
  __builtin_amdgcn_s_barrier();
  rd_a(rcA + ((unsigned)AOFF(0, 0) << 1), aFx);
  rd_b(rcB + ((unsigned)BOFF(0, 0) << 1), bF0);

  for (int T = 0; T < NT; ++T) {
    const int b = T & 1;

    // -- q0: MFMA(mh0,nh0); issue bF1(T) reads; stage B-nh0(T+1)
    rd_b(rcB + ((unsigned)BOFF(b, 1) << 1), bF1);
    if (T + 1 < NT) stage_B_half(B, bcol, (T + 1) * BK, 0, lds + BOFF(b ^ 1, 0), t);
    LGKM(4);
    MFMA16(aFx, bF0, 0, 0);
    __builtin_amdgcn_s_barrier();

    // -- q1: MFMA(mh0,nh1); issue aFy(T) reads; stage A-mh0(T+2)
    rd_a(rcA + ((unsigned)AOFF(b, 1) << 1), aFy);
    if (T + 2 < NT) stage_A_half(A, brow, (T + 2) * BK, 0, lds + AOFF(b, 0), t);
    LGKM(8);
    MFMA16(aFx, bF1, 0, 1);
    __builtin_amdgcn_s_barrier();

    // -- q2: MFMA(mh1,nh1); no reads; stage B-nh1(T+2); vmcnt once/tile
    if (T + 2 < NT) stage_B_half(B, bcol, (T + 2) * BK, 1, lds + BOFF(b, 1), t);
    LGKM(0);
    MFMA16(aFy, bF1, 1, 1);
    if (T < NT - 2)
      VMW(4);
    else if (T == NT - 2)
      VMW(0);
    __builtin_amdgcn_s_barrier();

    // -- q3: MFMA(mh1,nh0); issue aFx'+bF0n(T+1) reads; stage A-mh1(T+2)
    if (T + 1 < NT) {
      rd_a(rcA + ((unsigned)AOFF(b ^ 1, 0) << 1), aFx);
      rd_b(rcB + ((unsigned)BOFF(b ^ 1, 0) << 1), bF0n);
      if (T + 2 < NT) stage_A_half(A, brow, (T + 2) * BK, 1, lds + AOFF(b, 1), t);
      LGKM(12);
      MFMA16(aFy, bF0, 1, 0);
#pragma unroll
      for (int ni = 0; ni < 2; ++ni)
#pragma unroll
        for (int kk = 0; kk < 2; ++kk) bF0[ni][kk] = bF0n[ni][kk];
    } else {
      LGKM(0);
      MFMA16(aFy, bF0, 1, 0);
    }
    __builtin_amdgcn_s_barrier();
  }

  // ---- epilogue R16: LDS-transposed vectorized C-write ----
  // All LDS reads/writes of the loop are drained (LGKM(0) + final barrier).
  // Slice = 32 rows x 256 cols f32, padded row stride 260 floats (1040 B:
  // 16B-aligned; fq-groups land on banks 0/16 -> 2 lanes/bank = free).
  // Slice s (0..7): global rows brow + s*32 .. +31; owned by waves with
  // wr == s>>2; within, m = {2*(s&3), 2*(s&3)+1}.
  {
    float* lf = (float*)&lds[0];  // 32*260*4 = 33280 B used (fits 128 KiB)
    // per-thread scale/bias (same gc set as before)
    float sc[4], bi[4];
#pragma unroll
    for (int n = 0; n < 4; ++n) {
      const int gc = bcol + wc * 64 + n * 16 + fr;
      sc[n] = scale[gc];
      bi[n] = bias[gc];
    }
    const int srow = t >> 4;          // 0..31  (store row within slice)
    const int scol4 = (t & 15) * 4;   // store col base (floats)
#pragma unroll
    for (int s = 0; s < 8; ++s) {
      const int kmh = s & 3;
      if (wr == (s >> 3 ? 1 : (s >> 2))) {  // wr == s>>2 (0..1)
#pragma unroll
        for (int dm = 0; dm < 2; ++dm) {
          const int m = 2 * kmh + dm;
#pragma unroll
          for (int n = 0; n < 4; ++n) {
            const int col = wc * 64 + n * 16 + fr;
#pragma unroll
            for (int j = 0; j < 4; ++j) {
              const int rin = dm * 16 + fq * 4 + j;  // row in slice
              lf[rin * 260 + col] = acc[m][n][j] * sc[n] + bi[n];
            }
          }
        }
      }
      __builtin_amdgcn_s_barrier();
      // stream slice out: 4 passes of dwordx4; lanes 0-15 contiguous 256 B
      float* gout = C + (size_t)(brow + s * 32 + srow) * N_DIM + bcol;
#pragma unroll
      for (int k = 0; k < 4; ++k) {
        const int c0 = scol4 + k * 64;
        f32x4 v = *(const f32x4*)&lf[srow * 260 + c0];
        *(f32x4*)&gout[c0] = v;
      }
      __builtin_amdgcn_s_barrier();  // slice fully read before overwrite
    }
  }
}

// ---------------- naive fallback (only if ws too small) ----------------

__global__ void naive_kernel(const float* __restrict__ x, const int* __restrict__ w,
                             const float* __restrict__ sc, const float* __restrict__ bi,
                             float* __restrict__ out) {
  size_t idx = (size_t)blockIdx.x * blockDim.x + threadIdx.x;
  int m = (int)(idx >> 12);
  int n = (int)(idx & 4095);
  const float* xr = x + (size_t)m * K_DIM;
  const int* wr = w + (size_t)n * K_DIM;
  float acc = 0.f;
  for (int k = 0; k < K_DIM; ++k) acc = fmaf(xr[k], (float)wr[k], acc);
  out[idx] = acc * sc[n] + bi[n];
}

extern "C" void kernel_launch(void* const* d_in, const int* in_sizes, int n_in,
                              void* d_out, int out_size, void* d_ws, size_t ws_size,
                              hipStream_t stream) {
  const float* x = (const float*)d_in[0];
  const int* w = (const int*)d_in[1];
  const float* scale = (const float*)d_in[2];
  const float* bias = (const float*)d_in[3];
  float* out = (float*)d_out;

  const long nx = (long)M_DIM * K_DIM;
  const long nw = (long)N_DIM * K_DIM;
  const size_t need = (size_t)nx * 2 + (size_t)nw * 2;  // 96 MiB

  if (ws_size >= need) {
    unsigned short* xb = (unsigned short*)d_ws;
    unsigned short* wb = xb + nx;
    cvt_fused_kernel<<<2048, 256, 0, stream>>>(x, w, xb, wb, nx, nw);
    gemm_bt_kernel<<<512, 512, 0, stream>>>(xb, wb, scale, bias, out);
  } else {
    naive_kernel<<<((long)M_DIM * N_DIM) / 256, 256, 0, stream>>>(x, w, scale, bias, out);
  }
}